// Round 3
// baseline (1036.036 us; speedup 1.0000x reference)
//
#include <hip/hip_runtime.h>

// ============================================================================
// 2-layer Elman RNN (tanh), SEQ=1024 B=256 F=64 H=128, fp32 in/out.
// Strategy: batch-parallel persistent kernel. 16 blocks x 256 thr (4 waves).
//   - block owns 16 batch rows; wave owns 32 hidden cols (2 MFMA 16x16 tiles).
//   - all weights held in registers as fp16 MFMA B-fragments (loaded once).
//   - h carried in fp32; MFMA inputs rounded to fp16 (err ~5e-4 worst case).
//   - software pipeline: iter t computes h0(t) and h1(t-1) -> ONE barrier/step.
//   - h exchanged via double-buffered LDS fp16 planes (stride 136 halves ->
//     conflict-free-ish b128 A-frag reads).
// k-mapping inside fragments is the SAME for A and B, so any internal k
// permutation cancels; only the C/D mapping (col=lane&15,row=(lane>>4)*4+i,
// HW-verified) must be exact.
// ============================================================================

#define SEQ   1024
#define BATCH 256
#define FDIM  64
#define HID   128

typedef __attribute__((ext_vector_type(8))) _Float16 half8;
typedef __attribute__((ext_vector_type(4))) float    f32x4;

#define MFMA16(a, b, c) __builtin_amdgcn_mfma_f32_16x16x32_f16((a), (b), (c), 0, 0, 0)

__device__ __forceinline__ float fast_tanh(float x) {
  // tanh(x) = 1 - 2/(exp2(2*log2e*x)+1); saturates to +-1 correctly.
  float e = __builtin_amdgcn_exp2f(x * 2.8853900817779268f);
  return 1.0f - 2.0f * __builtin_amdgcn_rcpf(e + 1.0f);
}

__device__ __forceinline__ half8 cvt8(float4 a, float4 b) {
  half8 h;
  h[0] = (_Float16)a.x; h[1] = (_Float16)a.y; h[2] = (_Float16)a.z; h[3] = (_Float16)a.w;
  h[4] = (_Float16)b.x; h[5] = (_Float16)b.y; h[6] = (_Float16)b.z; h[7] = (_Float16)b.w;
  return h;
}

__device__ __forceinline__ half8 h8zero() {
  half8 v;
#pragma unroll
  for (int j = 0; j < 8; ++j) v[j] = (_Float16)0.0f;
  return v;
}

// B-fragment for output col `row` of W (row-major, leading dim ld), k-chunk
// base k0: lane holds W[row][k0..k0+7] as fp16.
__device__ __forceinline__ half8 load_w_frag(const float* __restrict__ W,
                                             int row, int k0, int ld) {
  const float4* p = (const float4*)(W + row * ld + k0);
  float4 a = p[0], b = p[1];
  return cvt8(a, b);
}

__global__ __launch_bounds__(256) void rnn_fused(
    const float* __restrict__ x,
    const float* __restrict__ Wih0, const float* __restrict__ bih0,
    const float* __restrict__ Whh0, const float* __restrict__ bhh0,
    const float* __restrict__ Wih1, const float* __restrict__ bih1,
    const float* __restrict__ Whh1, const float* __restrict__ bhh1,
    float* __restrict__ out)
{
  // [parity][layer][row 16][col 136(pad)] fp16
  __shared__ alignas(16) _Float16 hp[2][2][16][136];
  const int tid  = threadIdx.x;
  const int wv   = tid >> 6;        // wave 0..3, owns hid cols [32wv,32wv+32)
  const int lane = tid & 63;
  const int r16  = lane & 15;
  const int g4   = lane >> 4;
  const int b0   = blockIdx.x << 4; // batch strip base

  // ---------------- weight fragments (registers, fp16) ----------------
  half8 Bih0[2][2], Bhh0[2][4], Bih1[2][4], Bhh1[2][4];
  float bias0[2], bias1[2];
#pragma unroll
  for (int n = 0; n < 2; ++n) {
    const int row = (wv << 5) + (n << 4) + r16; // global hid col of this tile
    const int k0  = g4 << 3;
#pragma unroll
    for (int q = 0; q < 2; ++q) Bih0[n][q] = load_w_frag(Wih0, row, q * 32 + k0, FDIM);
#pragma unroll
    for (int q = 0; q < 4; ++q) {
      Bhh0[n][q] = load_w_frag(Whh0, row, q * 32 + k0, HID);
      Bih1[n][q] = load_w_frag(Wih1, row, q * 32 + k0, HID);
      Bhh1[n][q] = load_w_frag(Whh1, row, q * 32 + k0, HID);
    }
    bias0[n] = bih0[row] + bhh0[row];
    bias1[n] = bih1[row] + bhh1[row];
  }

  // ---------------- state ----------------
  half8 h0A[4], h1A[4], xA[2];
#pragma unroll
  for (int q = 0; q < 4; ++q) { h0A[q] = h8zero(); h1A[q] = h8zero(); }

  // x prefetch: lane reads x[t][b0+r16][{8g4..8g4+7, 32+8g4..}]
  const float* xrow = x + (b0 + r16) * FDIM + (g4 << 3);
  float4 xp[4];
  xp[0] = *(const float4*)(xrow);
  xp[1] = *(const float4*)(xrow + 4);
  xp[2] = *(const float4*)(xrow + 32);
  xp[3] = *(const float4*)(xrow + 36);
  const float* xnext = xrow + BATCH * FDIM;

  // LDS exchange pointers
  _Float16* wbase = &hp[0][0][g4 << 2][(wv << 5) + r16]; // + L*2176 + i*136 + n*16
  const _Float16* rbase = &hp[0][0][r16][g4 << 3];       // + L*2176 + q*32

  // y1 store base: elem (n,i) at  + (t-1)*B*H + i*H + n*16
  float* ybase = out + (size_t)(b0 + (g4 << 2)) * HID + (wv << 5) + r16;

  float h0f[2][4]; // fp32 h0(t) of this wave's tiles (last computed)
  float h1f[2][4]; // fp32 h1(t-1)

#pragma unroll 2
  for (int t = 0; t < SEQ; ++t) {
    // x(t) fragments
    xA[0] = cvt8(xp[0], xp[1]);
    xA[1] = cvt8(xp[2], xp[3]);
    if (t < SEQ - 1) { // prefetch x(t+1)
      xp[0] = *(const float4*)(xnext);
      xp[1] = *(const float4*)(xnext + 4);
      xp[2] = *(const float4*)(xnext + 32);
      xp[3] = *(const float4*)(xnext + 36);
      xnext += BATCH * FDIM;
    }

    // ---- layer 0: h0(t) = tanh(bias0 + x(t)Wih0^T + h0(t-1)Whh0^T) ----
#pragma unroll
    for (int n = 0; n < 2; ++n) {
      f32x4 acc = {bias0[n], bias0[n], bias0[n], bias0[n]};
      acc = MFMA16(xA[0], Bih0[n][0], acc);
      acc = MFMA16(xA[1], Bih0[n][1], acc);
#pragma unroll
      for (int q = 0; q < 4; ++q) acc = MFMA16(h0A[q], Bhh0[n][q], acc);
#pragma unroll
      for (int i = 0; i < 4; ++i) h0f[n][i] = fast_tanh(acc[i]);
    }

    // ---- layer 1 (lagged): h1(t-1) = tanh(bias1 + h0(t-1)Wih1^T + h1(t-2)Whh1^T)
#pragma unroll
    for (int n = 0; n < 2; ++n) {
      f32x4 acc = {bias1[n], bias1[n], bias1[n], bias1[n]};
#pragma unroll
      for (int q = 0; q < 4; ++q) acc = MFMA16(h0A[q], Bih1[n][q], acc);
#pragma unroll
      for (int q = 0; q < 4; ++q) acc = MFMA16(h1A[q], Bhh1[n][q], acc);
#pragma unroll
      for (int i = 0; i < 4; ++i) h1f[n][i] = fast_tanh(acc[i]);
    }

    // store y1[t-1] (h1f is garbage at t==0: h1(-1) is never stored)
    if (t > 0) {
      float* yo = ybase + (size_t)(t - 1) * (BATCH * HID);
#pragma unroll
      for (int n = 0; n < 2; ++n)
#pragma unroll
        for (int i = 0; i < 4; ++i) yo[i * HID + n * 16] = h1f[n][i];
    }

    // ---- exchange: write h0(t), h1(t-1) as fp16; barrier; read A-frags ----
    {
      _Float16* w = wbase + (t & 1) * 4352;
#pragma unroll
      for (int n = 0; n < 2; ++n)
#pragma unroll
        for (int i = 0; i < 4; ++i) {
          w[i * 136 + n * 16]        = (_Float16)h0f[n][i];
          w[2176 + i * 136 + n * 16] = (_Float16)h1f[n][i];
        }
    }
    __syncthreads();
    {
      const _Float16* r = rbase + (t & 1) * 4352;
#pragma unroll
      for (int q = 0; q < 4; ++q) {
        h0A[q] = *(const half8*)(r + q * 32);
        h1A[q] = *(const half8*)(r + 2176 + q * 32);
      }
    }
    if (t == 0) { // h1(-1) must be 0, not the garbage we just exchanged
#pragma unroll
      for (int q = 0; q < 4; ++q) h1A[q] = h8zero();
    }
  }

  // ---- epilogue: h1(1023), y1[1023], h_n ----
  float h1l[2][4];
#pragma unroll
  for (int n = 0; n < 2; ++n) {
    f32x4 acc = {bias1[n], bias1[n], bias1[n], bias1[n]};
#pragma unroll
    for (int q = 0; q < 4; ++q) acc = MFMA16(h0A[q], Bih1[n][q], acc);
#pragma unroll
    for (int q = 0; q < 4; ++q) acc = MFMA16(h1A[q], Bhh1[n][q], acc);
#pragma unroll
    for (int i = 0; i < 4; ++i) h1l[n][i] = fast_tanh(acc[i]);
  }
  {
    float* yo = ybase + (size_t)(SEQ - 1) * (BATCH * HID);
#pragma unroll
    for (int n = 0; n < 2; ++n)
#pragma unroll
      for (int i = 0; i < 4; ++i) yo[i * HID + n * 16] = h1l[n][i];
  }
  // h_n: [2][B][H] at offset SEQ*B*H. h0f holds h0(1023) from the last iter.
  {
    float* hn0 = out + (size_t)SEQ * BATCH * HID +
                 (size_t)(b0 + (g4 << 2)) * HID + (wv << 5) + r16;
    float* hn1 = hn0 + BATCH * HID;
#pragma unroll
    for (int n = 0; n < 2; ++n)
#pragma unroll
      for (int i = 0; i < 4; ++i) {
        hn0[i * HID + n * 16] = h0f[n][i];
        hn1[i * HID + n * 16] = h1l[n][i];
      }
  }
}

extern "C" void kernel_launch(void* const* d_in, const int* in_sizes, int n_in,
                              void* d_out, int out_size, void* d_ws, size_t ws_size,
                              hipStream_t stream) {
  (void)in_sizes; (void)n_in; (void)out_size; (void)d_ws; (void)ws_size;
  const float* x    = (const float*)d_in[0];
  const float* Wih0 = (const float*)d_in[1];
  const float* bih0 = (const float*)d_in[2];
  const float* Whh0 = (const float*)d_in[3];
  const float* bhh0 = (const float*)d_in[4];
  const float* Wih1 = (const float*)d_in[5];
  const float* bih1 = (const float*)d_in[6];
  const float* Whh1 = (const float*)d_in[7];
  const float* bhh1 = (const float*)d_in[8];
  rnn_fused<<<16, 256, 0, stream>>>(x, Wih0, bih0, Whh0, bhh0,
                                    Wih1, bih1, Whh1, bhh1, (float*)d_out);
}

// Round 5
// 1032.202 us; speedup vs baseline: 1.0037x; 1.0037x over previous
//
#include <hip/hip_runtime.h>

// ============================================================================
// 2-layer Elman RNN (tanh), SEQ=1024 B=256 F=64 H=128, fp32 in/out.
// R4 changes vs R3 (896us, VGPR=128, AGPR churn + vmcnt barrier drain):
//   A. __launch_bounds__(256,1): full register budget -> no accvgpr churn.
//   B. custom barrier (s_waitcnt lgkmcnt(0); s_barrier): __syncthreads was
//      draining vmcnt(0) = y1-store HBM latency on the critical path.
//   C. packed b32 LDS exchange via permuted k->slot map (A/B frags only need
//      IDENTICAL k maps; weights gathered with matching permutation at init).
//      8x ds_write_b32 per step instead of 16x ds_write_b16.
//   D. split MFMA acc chains (3+3 / 4+4) to halve dependent-latency depth.
// Slot map for h planes: slot S = c_lsb*8 + c_hi  (c = hid col, c_hi=c>>4).
//   write: thread (r16,g4,wv) packs (n=0,n=1) -> half2 at row=g4*4+i,
//          slot r16*8+wv*2  (4B-aligned b32 write).
//   read:  A-frag q = b128 at row=r16, slots [q*32+g4*8, +8): elem j <-> hid
//          col j*16 + q*4 + g4. Weight frags use the same (q,g4,j)->k gather.
// x/Bih0 keep the contiguous k map (independent pair).
// ============================================================================

#define SEQ   1024
#define BATCH 256
#define FDIM  64
#define HID   128

typedef __attribute__((ext_vector_type(8))) _Float16 half8;
typedef __attribute__((ext_vector_type(2))) _Float16 half2v;
typedef __attribute__((ext_vector_type(4))) float    f32x4;

#define MFMA16(a, b, c) __builtin_amdgcn_mfma_f32_16x16x32_f16((a), (b), (c), 0, 0, 0)

__device__ __forceinline__ void lds_barrier() {
  // LDS-only fence + barrier: do NOT drain vmcnt (y1 stores / x prefetch).
  asm volatile("s_waitcnt lgkmcnt(0)\n\ts_barrier" ::: "memory");
}

__device__ __forceinline__ float fast_tanh(float x) {
  float e = __builtin_amdgcn_exp2f(x * 2.8853900817779268f);
  return 1.0f - 2.0f * __builtin_amdgcn_rcpf(e + 1.0f);
}

__device__ __forceinline__ half8 cvt8(float4 a, float4 b) {
  half8 h;
  h[0] = (_Float16)a.x; h[1] = (_Float16)a.y; h[2] = (_Float16)a.z; h[3] = (_Float16)a.w;
  h[4] = (_Float16)b.x; h[5] = (_Float16)b.y; h[6] = (_Float16)b.z; h[7] = (_Float16)b.w;
  return h;
}

__device__ __forceinline__ half8 h8zero() {
  half8 v;
#pragma unroll
  for (int j = 0; j < 8; ++j) v[j] = (_Float16)0.0f;
  return v;
}

// Contiguous-k B-fragment (for Wih0, paired with x): lane holds W[row][k0..k0+7].
__device__ __forceinline__ half8 load_w_frag(const float* __restrict__ W,
                                             int row, int k0, int ld) {
  const float4* p = (const float4*)(W + row * ld + k0);
  float4 a = p[0], b = p[1];
  return cvt8(a, b);
}

// Permuted-k B-fragment (for h-paired weights): elem j <-> k = j*16 + q*4 + g4.
__device__ __forceinline__ half8 load_w_perm(const float* __restrict__ W,
                                             int row, int q, int g4, int ld) {
  const float* p = W + row * ld + q * 4 + g4;
  half8 h;
#pragma unroll
  for (int j = 0; j < 8; ++j) h[j] = (_Float16)p[j * 16];
  return h;
}

__global__ __launch_bounds__(256, 1) void rnn_fused(
    const float* __restrict__ x,
    const float* __restrict__ Wih0, const float* __restrict__ bih0,
    const float* __restrict__ Whh0, const float* __restrict__ bhh0,
    const float* __restrict__ Wih1, const float* __restrict__ bih1,
    const float* __restrict__ Whh1, const float* __restrict__ bhh1,
    float* __restrict__ out)
{
  // [parity][layer][row 16][slot 136(pad)] fp16
  __shared__ alignas(16) _Float16 hp[2][2][16][136];
  const int tid  = threadIdx.x;
  const int wv   = tid >> 6;
  const int lane = tid & 63;
  const int r16  = lane & 15;
  const int g4   = lane >> 4;
  const int b0   = blockIdx.x << 4;

  // ---------------- weight fragments ----------------
  half8 Bih0[2][2], Bhh0[2][4], Bih1[2][4], Bhh1[2][4];
  float bias0[2], bias1[2];
#pragma unroll
  for (int n = 0; n < 2; ++n) {
    const int row = (wv << 5) + (n << 4) + r16;
#pragma unroll
    for (int q = 0; q < 2; ++q) Bih0[n][q] = load_w_frag(Wih0, row, q * 32 + (g4 << 3), FDIM);
#pragma unroll
    for (int q = 0; q < 4; ++q) {
      Bhh0[n][q] = load_w_perm(Whh0, row, q, g4, HID);
      Bih1[n][q] = load_w_perm(Wih1, row, q, g4, HID);
      Bhh1[n][q] = load_w_perm(Whh1, row, q, g4, HID);
    }
    bias0[n] = bih0[row] + bhh0[row];
    bias1[n] = bih1[row] + bhh1[row];
  }

  // ---------------- state ----------------
  half8 h0A[4], h1A[4], xA[2];
#pragma unroll
  for (int q = 0; q < 4; ++q) { h0A[q] = h8zero(); h1A[q] = h8zero(); }

  const float* xrow = x + (b0 + r16) * FDIM + (g4 << 3);
  float4 xp[4];
  xp[0] = *(const float4*)(xrow);
  xp[1] = *(const float4*)(xrow + 4);
  xp[2] = *(const float4*)(xrow + 32);
  xp[3] = *(const float4*)(xrow + 36);
  const float* xnext = xrow + BATCH * FDIM;

  // LDS pointers (half units). write row = g4*4+i, slot = r16*8 + wv*2.
  _Float16* wbase = &hp[0][0][g4 << 2][(r16 << 3) + (wv << 1)];
  const _Float16* rbase = &hp[0][0][r16][g4 << 3];

  float* ybase = out + (size_t)(b0 + (g4 << 2)) * HID + (wv << 5) + r16;

  float h0f[2][4];
  float h1f[2][4];

#pragma unroll 2
  for (int t = 0; t < SEQ; ++t) {
    xA[0] = cvt8(xp[0], xp[1]);
    xA[1] = cvt8(xp[2], xp[3]);
    if (t < SEQ - 1) {
      xp[0] = *(const float4*)(xnext);
      xp[1] = *(const float4*)(xnext + 4);
      xp[2] = *(const float4*)(xnext + 32);
      xp[3] = *(const float4*)(xnext + 36);
      xnext += BATCH * FDIM;
    }

    _Float16* w = wbase + (t & 1) * 4352;

    // ---- layer 0: h0(t) = tanh(bias0 + x(t)Wih0^T + h0(t-1)Whh0^T) ----
#pragma unroll
    for (int n = 0; n < 2; ++n) {
      f32x4 a0 = {bias0[n], bias0[n], bias0[n], bias0[n]};
      f32x4 a1 = {0.f, 0.f, 0.f, 0.f};
      a0 = MFMA16(xA[0], Bih0[n][0], a0);
      a1 = MFMA16(xA[1], Bih0[n][1], a1);
      a0 = MFMA16(h0A[0], Bhh0[n][0], a0);
      a1 = MFMA16(h0A[1], Bhh0[n][1], a1);
      a0 = MFMA16(h0A[2], Bhh0[n][2], a0);
      a1 = MFMA16(h0A[3], Bhh0[n][3], a1);
#pragma unroll
      for (int i = 0; i < 4; ++i) h0f[n][i] = fast_tanh(a0[i] + a1[i]);
    }
    // write h0(t) plane early (overlaps with layer-1 compute)
#pragma unroll
    for (int i = 0; i < 4; ++i) {
      half2v v; v[0] = (_Float16)h0f[0][i]; v[1] = (_Float16)h0f[1][i];
      *(half2v*)(w + i * 136) = v;
    }

    // ---- layer 1 (lagged): h1(t-1) = tanh(bias1 + h0(t-1)Wih1^T + h1(t-2)Whh1^T)
#pragma unroll
    for (int n = 0; n < 2; ++n) {
      f32x4 a0 = {bias1[n], bias1[n], bias1[n], bias1[n]};
      f32x4 a1 = {0.f, 0.f, 0.f, 0.f};
      a0 = MFMA16(h0A[0], Bih1[n][0], a0);
      a1 = MFMA16(h0A[1], Bih1[n][1], a1);
      a0 = MFMA16(h0A[2], Bih1[n][2], a0);
      a1 = MFMA16(h0A[3], Bih1[n][3], a1);
      a0 = MFMA16(h1A[0], Bhh1[n][0], a0);
      a1 = MFMA16(h1A[1], Bhh1[n][1], a1);
      a0 = MFMA16(h1A[2], Bhh1[n][2], a0);
      a1 = MFMA16(h1A[3], Bhh1[n][3], a1);
#pragma unroll
      for (int i = 0; i < 4; ++i) h1f[n][i] = fast_tanh(a0[i] + a1[i]);
    }
#pragma unroll
    for (int i = 0; i < 4; ++i) {
      half2v v; v[0] = (_Float16)h1f[0][i]; v[1] = (_Float16)h1f[1][i];
      *(half2v*)(w + 2176 + i * 136) = v;
    }

    // y1[t-1] global store (fire-and-forget; NOT drained by our barrier)
    if (t > 0) {
      float* yo = ybase + (size_t)(t - 1) * (BATCH * HID);
#pragma unroll
      for (int n = 0; n < 2; ++n)
#pragma unroll
        for (int i = 0; i < 4; ++i) yo[i * HID + n * 16] = h1f[n][i];
    }

    lds_barrier();
    {
      const _Float16* r = rbase + (t & 1) * 4352;
#pragma unroll
      for (int q = 0; q < 4; ++q) {
        h0A[q] = *(const half8*)(r + q * 32);
        h1A[q] = *(const half8*)(r + 2176 + q * 32);
      }
    }
    if (t == 0) {
#pragma unroll
      for (int q = 0; q < 4; ++q) h1A[q] = h8zero();
    }
  }

  // ---- epilogue: h1(1023), y1[1023], h_n ----
  float h1l[2][4];
#pragma unroll
  for (int n = 0; n < 2; ++n) {
    f32x4 a0 = {bias1[n], bias1[n], bias1[n], bias1[n]};
    f32x4 a1 = {0.f, 0.f, 0.f, 0.f};
    a0 = MFMA16(h0A[0], Bih1[n][0], a0);
    a1 = MFMA16(h0A[1], Bih1[n][1], a1);
    a0 = MFMA16(h0A[2], Bih1[n][2], a0);
    a1 = MFMA16(h0A[3], Bih1[n][3], a1);
    a0 = MFMA16(h1A[0], Bhh1[n][0], a0);
    a1 = MFMA16(h1A[1], Bhh1[n][1], a1);
    a0 = MFMA16(h1A[2], Bhh1[n][2], a0);
    a1 = MFMA16(h1A[3], Bhh1[n][3], a1);
#pragma unroll
    for (int i = 0; i < 4; ++i) h1l[n][i] = fast_tanh(a0[i] + a1[i]);
  }
  {
    float* yo = ybase + (size_t)(SEQ - 1) * (BATCH * HID);
#pragma unroll
    for (int n = 0; n < 2; ++n)
#pragma unroll
      for (int i = 0; i < 4; ++i) yo[i * HID + n * 16] = h1l[n][i];
  }
  {
    float* hn0 = out + (size_t)SEQ * BATCH * HID +
                 (size_t)(b0 + (g4 << 2)) * HID + (wv << 5) + r16;
    float* hn1 = hn0 + BATCH * HID;
#pragma unroll
    for (int n = 0; n < 2; ++n)
#pragma unroll
      for (int i = 0; i < 4; ++i) {
        hn0[i * HID + n * 16] = h0f[n][i];
        hn1[i * HID + n * 16] = h1l[n][i];
      }
  }
}

extern "C" void kernel_launch(void* const* d_in, const int* in_sizes, int n_in,
                              void* d_out, int out_size, void* d_ws, size_t ws_size,
                              hipStream_t stream) {
  (void)in_sizes; (void)n_in; (void)out_size; (void)d_ws; (void)ws_size;
  const float* x    = (const float*)d_in[0];
  const float* Wih0 = (const float*)d_in[1];
  const float* bih0 = (const float*)d_in[2];
  const float* Whh0 = (const float*)d_in[3];
  const float* bhh0 = (const float*)d_in[4];
  const float* Wih1 = (const float*)d_in[5];
  const float* bih1 = (const float*)d_in[6];
  const float* Whh1 = (const float*)d_in[7];
  const float* bhh1 = (const float*)d_in[8];
  rnn_fused<<<16, 256, 0, stream>>>(x, Wih0, bih0, Whh0, bhh0,
                                    Wih1, bih1, Whh1, bhh1, (float*)d_out);
}